// Round 1
// baseline (268.985 us; speedup 1.0000x reference)
//
#include <hip/hip_runtime.h>

#define D 64
#define SMOOTH 0.5f

// ---------------------------------------------------------------------------
// Kernel 1: degree count via atomics. deg[j] = #edges with col==j
// ---------------------------------------------------------------------------
__global__ void deg_kernel(const int* __restrict__ col, float* __restrict__ deg,
                           int n_edges) {
    int i = blockIdx.x * blockDim.x + threadIdx.x;
    if (i < n_edges) atomicAdd(&deg[col[i]], 1.0f);
}

// ---------------------------------------------------------------------------
// Kernel 2: deg -> d = (deg+1)^-0.5  (in place)
// ---------------------------------------------------------------------------
__global__ void rsqrt_kernel(float* __restrict__ deg, int n) {
    int i = blockIdx.x * blockDim.x + threadIdx.x;
    if (i < n) deg[i] = rsqrtf(deg[i] + 1.0f);
}

// ---------------------------------------------------------------------------
// Kernel 3: support = x @ W.T + b   (W is [out=64, in=64], row-major)
// One block of 256 threads handles 4 nodes; W staged in LDS (padded +1:
// lanes o=0..63 read Ws[o][k] -> banks (o+k)%32, 2 lanes/bank = free).
// ---------------------------------------------------------------------------
__global__ __launch_bounds__(256) void support_kernel(
    const float* __restrict__ x, const float* __restrict__ W,
    const float* __restrict__ b, float* __restrict__ support, int n_nodes) {
    __shared__ float Ws[D][D + 1];
    __shared__ float xs[4][D];
    const int t = threadIdx.x;
    for (int i = t; i < D * D; i += 256) Ws[i / D][i % D] = W[i];

    const int node0 = blockIdx.x * 4;
    const int local = t >> 6;       // 0..3
    const int o     = t & 63;       // output feature
    const int node  = node0 + local;
    if (node < n_nodes) xs[local][o] = x[(size_t)node * D + o];
    __syncthreads();

    if (node < n_nodes) {
        float acc = b[o];
        #pragma unroll
        for (int k = 0; k < D; ++k) acc += xs[local][k] * Ws[o][k];
        support[(size_t)node * D + o] = acc;
    }
}

// ---------------------------------------------------------------------------
// Kernel 4: edge scatter. One 64-lane wave per edge:
//   scatter[row][k] += support[col][k] * d[col]
// ---------------------------------------------------------------------------
__global__ __launch_bounds__(256) void scatter_kernel(
    const int* __restrict__ erow, const int* __restrict__ ecol,
    const float* __restrict__ support, const float* __restrict__ d,
    float* __restrict__ scatter, int n_edges) {
    long long gid = (long long)blockIdx.x * blockDim.x + threadIdx.x;
    int e    = (int)(gid >> 6);
    int lane = (int)(gid & 63);
    if (e < n_edges) {
        int r = erow[e];
        int c = ecol[e];
        float v = support[(size_t)c * D + lane] * d[c];
        atomicAdd(&scatter[(size_t)r * D + lane], v);
    }
}

// ---------------------------------------------------------------------------
// Kernel 5: epilogue. out = ((scatter + s*d)*d*SMOOTH + s) / (1+SMOOTH)
// where s = support (currently stored in d_out). float4 vectorized.
// ---------------------------------------------------------------------------
__global__ void final_kernel(float* __restrict__ out,
                             const float* __restrict__ scatter,
                             const float* __restrict__ d, int n_nodes) {
    int i = blockIdx.x * blockDim.x + threadIdx.x;  // float4 index
    int total = n_nodes * (D / 4);
    if (i < total) {
        int node = i / (D / 4);
        float di = d[node];
        float4 s  = ((const float4*)out)[i];
        float4 sc = ((const float4*)scatter)[i];
        const float inv = 1.0f / (1.0f + SMOOTH);
        float4 r;
        r.x = ((sc.x + s.x * di) * di * SMOOTH + s.x) * inv;
        r.y = ((sc.y + s.y * di) * di * SMOOTH + s.y) * inv;
        r.z = ((sc.z + s.z * di) * di * SMOOTH + s.z) * inv;
        r.w = ((sc.w + s.w * di) * di * SMOOTH + s.w) * inv;
        ((float4*)out)[i] = r;
    }
}

extern "C" void kernel_launch(void* const* d_in, const int* in_sizes, int n_in,
                              void* d_out, int out_size, void* d_ws, size_t ws_size,
                              hipStream_t stream) {
    const float* x    = (const float*)d_in[0];
    const float* W    = (const float*)d_in[1];
    const float* b    = (const float*)d_in[2];
    const int*   erow = (const int*)d_in[3];
    const int*   ecol = (const int*)d_in[4];
    float* out = (float*)d_out;

    const int n_nodes = in_sizes[0] / D;
    const int n_edges = in_sizes[3];

    // ws layout: [scatter: n_nodes*D f32][deg/d: n_nodes f32]
    float* scatter = (float*)d_ws;
    float* deg     = scatter + (size_t)n_nodes * D;

    // zero accumulators every call (graph replays must be deterministic)
    hipMemsetAsync(d_ws, 0, (size_t)(n_nodes * D + n_nodes) * sizeof(float), stream);

    deg_kernel<<<(n_edges + 255) / 256, 256, 0, stream>>>(ecol, deg, n_edges);
    rsqrt_kernel<<<(n_nodes + 255) / 256, 256, 0, stream>>>(deg, n_nodes);

    // support staged in d_out
    support_kernel<<<(n_nodes + 3) / 4, 256, 0, stream>>>(x, W, b, out, n_nodes);

    long long sc_threads = (long long)n_edges * 64;
    scatter_kernel<<<(int)((sc_threads + 255) / 256), 256, 0, stream>>>(
        erow, ecol, out, deg, scatter, n_edges);

    int total4 = n_nodes * (D / 4);
    final_kernel<<<(total4 + 255) / 256, 256, 0, stream>>>(out, scatter, deg, n_nodes);
}

// Round 2
// 194.174 us; speedup vs baseline: 1.3853x; 1.3853x over previous
//
#include <hip/hip_runtime.h>

#define D 64
#define SMOOTH 0.5f
#define SCAN_B 256   // scan block size; requires ceil(n_nodes/256) <= 256 (50000 -> 196, ok)

// ---------------------------------------------------------------------------
// Kernel 1: per-node edge histograms. rowcnt[r]++, colcnt[c]++ per edge.
// ---------------------------------------------------------------------------
__global__ void hist_kernel(const int* __restrict__ erow, const int* __restrict__ ecol,
                            int* __restrict__ rowcnt, int* __restrict__ colcnt, int ne) {
    int i = blockIdx.x * blockDim.x + threadIdx.x;
    if (i < ne) {
        atomicAdd(&rowcnt[erow[i]], 1);
        atomicAdd(&colcnt[ecol[i]], 1);
    }
}

// ---------------------------------------------------------------------------
// Kernel 2: per-block sums of rowcnt (scan phase A)
// ---------------------------------------------------------------------------
__global__ __launch_bounds__(SCAN_B) void blocksum_kernel(
    const int* __restrict__ rowcnt, int* __restrict__ blocksum, int n) {
    __shared__ int s[SCAN_B];
    int i = blockIdx.x * SCAN_B + threadIdx.x;
    s[threadIdx.x] = (i < n) ? rowcnt[i] : 0;
    __syncthreads();
    for (int off = SCAN_B / 2; off > 0; off >>= 1) {
        if ((int)threadIdx.x < off) s[threadIdx.x] += s[threadIdx.x + off];
        __syncthreads();
    }
    if (threadIdx.x == 0) blocksum[blockIdx.x] = s[0];
}

// ---------------------------------------------------------------------------
// Kernel 3: exclusive scan of block sums (single block; nb <= 256)
// ---------------------------------------------------------------------------
__global__ __launch_bounds__(SCAN_B) void scanpartials_kernel(
    const int* __restrict__ blocksum, int* __restrict__ blockoff, int nb) {
    __shared__ int s[SCAN_B];
    int t = threadIdx.x;
    int v = (t < nb) ? blocksum[t] : 0;
    s[t] = v;
    __syncthreads();
    for (int off = 1; off < SCAN_B; off <<= 1) {
        int add = (t >= off) ? s[t - off] : 0;
        __syncthreads();
        s[t] += add;
        __syncthreads();
    }
    if (t < nb) blockoff[t] = s[t] - v;   // exclusive
}

// ---------------------------------------------------------------------------
// Kernel 4: final scan -> row_start & cursor; also d = rsqrt(colcnt+1)
// ---------------------------------------------------------------------------
__global__ __launch_bounds__(SCAN_B) void finalscan_kernel(
    const int* __restrict__ rowcnt, const int* __restrict__ colcnt,
    const int* __restrict__ blockoff, int* __restrict__ row_start,
    int* __restrict__ cursor, float* __restrict__ d, int n) {
    __shared__ int s[SCAN_B];
    int t = threadIdx.x;
    int i = blockIdx.x * SCAN_B + t;
    int v = (i < n) ? rowcnt[i] : 0;
    s[t] = v;
    __syncthreads();
    for (int off = 1; off < SCAN_B; off <<= 1) {
        int add = (t >= off) ? s[t - off] : 0;
        __syncthreads();
        s[t] += add;
        __syncthreads();
    }
    if (i < n) {
        int excl = s[t] - v + blockoff[blockIdx.x];
        row_start[i] = excl;
        cursor[i]    = excl;
        d[i] = rsqrtf((float)colcnt[i] + 1.0f);
    }
}

// ---------------------------------------------------------------------------
// Kernel 5: bucket edges into CSR. list[pos] = col index of edge.
// (within-row order is nondeterministic; f32 sum-order tolerance is ample)
// ---------------------------------------------------------------------------
__global__ void fill_kernel(const int* __restrict__ erow, const int* __restrict__ ecol,
                            int* __restrict__ cursor, int* __restrict__ list, int ne) {
    int i = blockIdx.x * blockDim.x + threadIdx.x;
    if (i < ne) {
        int r = erow[i];
        int pos = atomicAdd(&cursor[r], 1);
        list[pos] = ecol[i];
    }
}

// ---------------------------------------------------------------------------
// Kernel 6: support = x @ W.T + b. One block = 4 nodes; W in LDS (+1 pad).
// ---------------------------------------------------------------------------
__global__ __launch_bounds__(256) void support_kernel(
    const float* __restrict__ x, const float* __restrict__ W,
    const float* __restrict__ b, float* __restrict__ support, int n_nodes) {
    __shared__ float Ws[D][D + 1];
    __shared__ float xs[4][D];
    const int t = threadIdx.x;
    for (int i = t; i < D * D; i += 256) Ws[i / D][i % D] = W[i];

    const int node0 = blockIdx.x * 4;
    const int local = t >> 6;
    const int o     = t & 63;
    const int node  = node0 + local;
    if (node < n_nodes) xs[local][o] = x[(size_t)node * D + o];
    __syncthreads();

    if (node < n_nodes) {
        float acc = b[o];
        #pragma unroll
        for (int k = 0; k < D; ++k) acc += xs[local][k] * Ws[o][k];
        support[(size_t)node * D + o] = acc;
    }
}

// ---------------------------------------------------------------------------
// Kernel 7: gather + fused epilogue. One 64-lane wave per output node.
//   acc = sum_{e in row r} support[col_e][lane] * d[col_e]
//   out = ((acc + s*d_r)*d_r*SMOOTH + s) / (1+SMOOTH)
// ---------------------------------------------------------------------------
__global__ __launch_bounds__(256) void gather_kernel(
    const float* __restrict__ support, const float* __restrict__ d,
    const int* __restrict__ row_start, const int* __restrict__ rowcnt,
    const int* __restrict__ list, float* __restrict__ out, int n) {
    long long gid = (long long)blockIdx.x * blockDim.x + threadIdx.x;
    int r    = (int)(gid >> 6);
    int lane = (int)(gid & 63);
    if (r >= n) return;

    float s  = support[(size_t)r * D + lane];
    float dr = d[r];
    int start = row_start[r];
    int cnt   = rowcnt[r];

    float acc = 0.0f;
    int j = 0;
    for (; j + 4 <= cnt; j += 4) {   // 4-way unroll: independent row loads for ILP
        int c0 = list[start + j + 0];
        int c1 = list[start + j + 1];
        int c2 = list[start + j + 2];
        int c3 = list[start + j + 3];
        float d0 = d[c0], d1 = d[c1], d2 = d[c2], d3 = d[c3];
        float v0 = support[(size_t)c0 * D + lane];
        float v1 = support[(size_t)c1 * D + lane];
        float v2 = support[(size_t)c2 * D + lane];
        float v3 = support[(size_t)c3 * D + lane];
        acc += v0 * d0 + v1 * d1 + v2 * d2 + v3 * d3;
    }
    for (; j < cnt; ++j) {
        int c = list[start + j];
        acc += support[(size_t)c * D + lane] * d[c];
    }

    float msg = acc + s * dr;
    out[(size_t)r * D + lane] = (msg * dr * SMOOTH + s) * (1.0f / (1.0f + SMOOTH));
}

extern "C" void kernel_launch(void* const* d_in, const int* in_sizes, int n_in,
                              void* d_out, int out_size, void* d_ws, size_t ws_size,
                              hipStream_t stream) {
    const float* x    = (const float*)d_in[0];
    const float* W    = (const float*)d_in[1];
    const float* b    = (const float*)d_in[2];
    const int*   erow = (const int*)d_in[3];
    const int*   ecol = (const int*)d_in[4];
    float* out = (float*)d_out;

    const int n_nodes = in_sizes[0] / D;
    const int n_edges = in_sizes[3];
    const int nblocks = (n_nodes + SCAN_B - 1) / SCAN_B;   // 196 <= 256

    // ws layout (4-byte units), all arrays 256B-aligned by padding to 64:
    size_t off = 0;
    float* support = (float*)d_ws + off;               off += (size_t)n_nodes * D;        // 3.2M
    int*   list    = (int*)d_ws + off;                 off += (size_t)n_edges;            // 800K
    int*   rowcnt  = (int*)d_ws + off;                 off += (size_t)((n_nodes + 63) & ~63);
    int*   colcnt  = (int*)d_ws + off;                 off += (size_t)((n_nodes + 63) & ~63);
    int*   row_start = (int*)d_ws + off;               off += (size_t)((n_nodes + 63) & ~63);
    int*   cursor  = (int*)d_ws + off;                 off += (size_t)((n_nodes + 63) & ~63);
    float* d       = (float*)d_ws + off;               off += (size_t)((n_nodes + 63) & ~63);
    int*   blocksum = (int*)d_ws + off;                off += 256;
    int*   blockoff = (int*)d_ws + off;                off += 256;

    // zero only the histograms (rowcnt, colcnt are adjacent)
    hipMemsetAsync(rowcnt, 0, 2 * (size_t)((n_nodes + 63) & ~63) * sizeof(int), stream);

    const int eblocks = (n_edges + 255) / 256;
    hist_kernel<<<eblocks, 256, 0, stream>>>(erow, ecol, rowcnt, colcnt, n_edges);

    blocksum_kernel<<<nblocks, SCAN_B, 0, stream>>>(rowcnt, blocksum, n_nodes);
    scanpartials_kernel<<<1, SCAN_B, 0, stream>>>(blocksum, blockoff, nblocks);
    finalscan_kernel<<<nblocks, SCAN_B, 0, stream>>>(rowcnt, colcnt, blockoff,
                                                     row_start, cursor, d, n_nodes);

    fill_kernel<<<eblocks, 256, 0, stream>>>(erow, ecol, cursor, list, n_edges);

    support_kernel<<<(n_nodes + 3) / 4, 256, 0, stream>>>(x, W, b, support, n_nodes);

    long long g_threads = (long long)n_nodes * 64;
    gather_kernel<<<(int)((g_threads + 255) / 256), 256, 0, stream>>>(
        support, d, row_start, rowcnt, list, out, n_nodes);
}